// Round 1
// baseline (505.910 us; speedup 1.0000x reference)
//
#include <hip/hip_runtime.h>
#include <hip/hip_bf16.h>

// GGCN: g1=relu(A@(x@W1)+b1); g2=relu(A@(g1@W2)+b2); out=relu(g2@Wd1+bd1)@Wd2+bd2
// N=16384, F=32, H=64, A is dense f32 [N][N] (1.07 GB, read twice -> HBM-bound).
// Strategy: bf16 MFMA (32x32x16) for the two A@H products, f32 accumulate.

typedef __bf16 bf16x8 __attribute__((ext_vector_type(8)));
typedef float  f32x16 __attribute__((ext_vector_type(16)));
typedef float  f32x4v __attribute__((ext_vector_type(4)));
typedef int    i32x4  __attribute__((ext_vector_type(4)));

#define NNODE 16384
#define KDIM  16384
#define HCOL  64

__device__ inline i32x4 pack8(f32x4v a, f32x4v b){
  bf16x8 t;
  t[0]=(__bf16)a[0]; t[1]=(__bf16)a[1]; t[2]=(__bf16)a[2]; t[3]=(__bf16)a[3];
  t[4]=(__bf16)b[0]; t[5]=(__bf16)b[1]; t[6]=(__bf16)b[2]; t[7]=(__bf16)b[3];
  return __builtin_bit_cast(i32x4, t);
}

// ---------------- big kernel: G = relu(A @ Ht^T + bias) ----------------
// block = 128 threads (2 waves). BM=32 rows. wave kw handles K-half kw.
// LDS: per (kw,buf): A-tile 32x64 bf16 (4KB), H-tile 64x64 bf16 (8KB). dbuf.
// XOR swizzle on 16B chunks: physical chunk = row*8 + (c ^ (row&7)).
__global__ __launch_bounds__(128) void gcn_layer_kernel(
    const float* __restrict__ A,      // [16384][16384] f32
    const __bf16* __restrict__ Ht,    // [64][16384] bf16 (transposed H)
    const float* __restrict__ bias,   // [64]
    float* __restrict__ G)            // [16384][64] f32
{
  __shared__ i32x4 sA[2*2*256];   // (kw,buf) x 32 rows x 8 chunks
  __shared__ i32x4 sH[2*2*512];   // (kw,buf) x 64 rows x 8 chunks

  const int tid  = threadIdx.x;
  const int lane = tid & 63;
  const int kw   = tid >> 6;          // K-half
  const int row0 = blockIdx.x * 32;

  const int rA0  = lane >> 3;         // 0..7 (staging row-in-group)
  const int ccA  = lane & 7;          // staging logical chunk
  const int swzA = ccA ^ rA0;         // swizzled chunk (rA0 < 8)
  const int r    = lane & 31;
  const int hsub = lane >> 5;         // 0/1 k-subgroup
  const int xs   = lane & 7;          // = r&7

  const size_t k0base = (size_t)kw * 8192;

  f32x4v ra[8]; i32x4 rh[8];

  const float* pA0 = A + (size_t)(row0 + rA0) * KDIM + k0base + (size_t)ccA*8;
  const i32x4* pH0 = (const i32x4*)Ht + (size_t)rA0 * (KDIM/8) + k0base/8 + ccA;

  auto stage_load = [&](int t){
    const float* pA = pA0 + (size_t)t*64;
    #pragma unroll
    for (int pi=0; pi<4; ++pi){
      const float* p = pA + (size_t)pi*8*KDIM;
      ra[2*pi]   = __builtin_nontemporal_load((const f32x4v*)p);       // A: streaming
      ra[2*pi+1] = __builtin_nontemporal_load((const f32x4v*)(p+4));
    }
    const i32x4* pH = pH0 + (size_t)t*8;
    #pragma unroll
    for (int pi=0; pi<8; ++pi)
      rh[pi] = pH[(size_t)pi*8*(KDIM/8)];                              // Ht: keep cached (L2)
  };

  auto stage_write = [&](int buf){
    i32x4* dA = &sA[(kw*2+buf)*256];
    #pragma unroll
    for (int pi=0; pi<4; ++pi)
      dA[(rA0 + pi*8)*8 + swzA] = pack8(ra[2*pi], ra[2*pi+1]);
    i32x4* dH = &sH[(kw*2+buf)*512];
    #pragma unroll
    for (int pi=0; pi<8; ++pi)
      dH[(rA0 + pi*8)*8 + swzA] = rh[pi];
  };

  f32x16 acc0 = {}; f32x16 acc1 = {};

  auto compute = [&](int buf){
    const i32x4* bA = &sA[(kw*2+buf)*256];
    const i32x4* bH = &sH[(kw*2+buf)*512];
    #pragma unroll
    for (int kk=0; kk<4; ++kk){
      int c = (kk*2 + hsub) ^ xs;
      bf16x8 a  = __builtin_bit_cast(bf16x8, bA[r*8 + c]);
      bf16x8 b0 = __builtin_bit_cast(bf16x8, bH[r*8 + c]);
      bf16x8 b1 = __builtin_bit_cast(bf16x8, bH[(r+32)*8 + c]);
      acc0 = __builtin_amdgcn_mfma_f32_32x32x16_bf16(a, b0, acc0, 0,0,0);
      acc1 = __builtin_amdgcn_mfma_f32_32x32x16_bf16(a, b1, acc1, 0,0,0);
    }
  };

  stage_load(0);
  stage_write(0);
  __syncthreads();
  for (int t=0; t<127; ++t){
    stage_load(t+1);          // issue next-tile loads before compute (latency hiding)
    compute(t&1);
    __syncthreads();
    stage_write((t+1)&1);
    __syncthreads();
  }
  compute(1);                 // tile 127 lives in buf 1
  __syncthreads();

  // split-K reduce (wave kw=1 -> LDS), then bias+relu+store by wave kw=0
  float* red = (float*)sA;    // reuse: 32*64 f32 = 8KB
  if (kw == 1){
    #pragma unroll
    for (int j=0; j<16; ++j){
      int rr = (j&3) + 8*(j>>2) + 4*hsub;   // C/D layout [m74/m101]
      red[rr*64 + r]      = acc0[j];
      red[rr*64 + 32 + r] = acc1[j];
    }
  }
  __syncthreads();
  if (kw == 0){
    #pragma unroll
    for (int j=0; j<16; ++j){
      int rr = (j&3) + 8*(j>>2) + 4*hsub;
      float v0 = acc0[j] + red[rr*64 + r]      + bias[r];
      float v1 = acc1[j] + red[rr*64 + 32 + r] + bias[32 + r];
      G[(size_t)(row0 + rr)*HCOL + r]      = fmaxf(v0, 0.f);
      G[(size_t)(row0 + rr)*HCOL + 32 + r] = fmaxf(v1, 0.f);
    }
  }
}

// ---------------- projection: out[h][n] = sum_f in[n][f]*W[f][h], bf16 out ----------------
template<int F>
__global__ __launch_bounds__(128) void proj_T_kernel(
    const float* __restrict__ in,   // [N][F]
    const float* __restrict__ W,    // [F][64]
    __bf16* __restrict__ out)       // [64][N]
{
  constexpr int FP = F + 4;
  __shared__ float sWt[64*FP];      // W transposed [h][f], padded
  __shared__ short sOut[64*136];    // [h][128 nodes], padded

  int tid = threadIdx.x;
  for (int e = tid; e < 64*F; e += 128){
    int h = e / F, j = e - h*F;
    sWt[h*FP + j] = W[j*64 + h];
  }
  __syncthreads();

  const size_t n = (size_t)blockIdx.x*128 + tid;
  float rowv[F];
  #pragma unroll
  for (int j=0; j<F; j+=4){
    f32x4v v = *(const f32x4v*)(in + n*F + j);
    rowv[j]=v[0]; rowv[j+1]=v[1]; rowv[j+2]=v[2]; rowv[j+3]=v[3];
  }
  #pragma unroll
  for (int h=0; h<64; ++h){
    float s = 0.f;
    #pragma unroll
    for (int j=0; j<F; j+=4){
      f32x4v w = *(const f32x4v*)&sWt[h*FP + j];
      s += rowv[j]*w[0] + rowv[j+1]*w[1] + rowv[j+2]*w[2] + rowv[j+3]*w[3];
    }
    sOut[h*136 + tid] = __builtin_bit_cast(short, (__bf16)s);
  }
  __syncthreads();

  const size_t n0 = (size_t)blockIdx.x*128;
  #pragma unroll
  for (int pi=0; pi<8; ++pi){
    int p = pi*128 + tid;
    int h = p >> 4, cc = p & 15;
    i32x4 v = *(const i32x4*)&sOut[h*136 + cc*8];
    *(i32x4*)(out + (size_t)h*NNODE + n0 + cc*8) = v;
  }
}

// ---------------- tail MLP: out[n] = relu(g2[n]@Wd1+bd1)@Wd2 + bd2 ----------------
__global__ __launch_bounds__(256) void tail_kernel(
    const float* __restrict__ g2,   // [N][64]
    const float* __restrict__ Wd1,  // [64][32]
    const float* __restrict__ bd1,  // [32]
    const float* __restrict__ Wd2,  // [32][1]
    const float* __restrict__ bd2,  // [1]
    float* __restrict__ outp)       // [N]
{
  __shared__ float sW[64*32];
  __shared__ float sb1[32], sw2[32];
  int tid = threadIdx.x;
  for (int e=tid; e<2048; e+=256) sW[e] = Wd1[e];
  if (tid < 32){ sb1[tid] = bd1[tid]; sw2[tid] = Wd2[tid]; }
  __syncthreads();

  size_t n = (size_t)blockIdx.x*256 + tid;
  float rv[64];
  #pragma unroll
  for (int j=0;j<64;j+=4){
    f32x4v v = *(const f32x4v*)(g2 + n*64 + j);
    rv[j]=v[0]; rv[j+1]=v[1]; rv[j+2]=v[2]; rv[j+3]=v[3];
  }
  float o = 0.f;
  #pragma unroll
  for (int c=0;c<32;++c){
    float s = sb1[c];
    #pragma unroll
    for (int j=0;j<64;++j) s += rv[j]*sW[j*32 + c];
    o += fmaxf(s, 0.f) * sw2[c];
  }
  outp[n] = o + bd2[0];
}

extern "C" void kernel_launch(void* const* d_in, const int* in_sizes, int n_in,
                              void* d_out, int out_size, void* d_ws, size_t ws_size,
                              hipStream_t stream)
{
  const float* x   = (const float*)d_in[0];
  const float* a   = (const float*)d_in[1];
  const float* W1  = (const float*)d_in[2];
  const float* b1  = (const float*)d_in[3];
  const float* W2  = (const float*)d_in[4];
  const float* b2  = (const float*)d_in[5];
  const float* Wd1 = (const float*)d_in[6];
  const float* bd1 = (const float*)d_in[7];
  const float* Wd2 = (const float*)d_in[8];
  const float* bd2 = (const float*)d_in[9];
  float* outp = (float*)d_out;

  char* ws = (char*)d_ws;                       // needs 12 MB
  __bf16* Ht1 = (__bf16*)(ws);                  // [64][16384] bf16, 2 MB
  __bf16* Ht2 = (__bf16*)(ws + (2u<<20));       // 2 MB
  float*  g1  = (float*)(ws + (4u<<20));        // [16384][64] f32, 4 MB
  float*  g2  = (float*)(ws + (8u<<20));        // 4 MB

  proj_T_kernel<32><<<128, 128, 0, stream>>>(x,  W1, Ht1);
  gcn_layer_kernel <<<512, 128, 0, stream>>>(a, Ht1, b1, g1);
  proj_T_kernel<64><<<128, 128, 0, stream>>>(g1, W2, Ht2);
  gcn_layer_kernel <<<512, 128, 0, stream>>>(a, Ht2, b2, g2);
  tail_kernel      <<<64, 256, 0, stream>>>(g2, Wd1, bd1, Wd2, bd2, outp);
}